// Round 2
// baseline (102.646 us; speedup 1.0000x reference)
//
#include <hip/hip_runtime.h>
#include <math.h>

// Problem constants: B=64, IN=1024, OUT=512, T=512, V_TH=1, TAU=16
#define BATCH   64
#define INS     1024
#define OUTS    512
#define TSTEPS  512
#define TAUF    16.0f
// log2(e)/TAU for exp(t/tau) == exp2(t * LOG2E_OVER_TAU)
#define LOG2E_OVER_TAU 0.0901684400555602f

// ---------------------------------------------------------------------------
// Fused pre-kernel: blocks [0,128) tiled weight transpose w[OUT,IN]->wT[IN,OUT];
// blocks [128,192) per-batch spike prep + counting sort by activation time.
//   alpha(t-s) = e^{-t/tau} * (t*A + C) for t > s,
//   A = exp(1 + s/tau)/tau,  C = -s*A,  t_on = floor(s)+1 in [1,256].
// Record per spike (sorted by t_on): {A, int_bits(i*OUTS*4 BYTE offset), C, t_on}
// (byte offset -> scan kernel gathers with uniform base + 32-bit voffset)
// Also writes starts[b][tau], tau in [0,257]: # spikes with t_on < tau.
// ---------------------------------------------------------------------------
#define TT 64
#define NTRANS ((INS / TT) * (OUTS / TT))   // 128 transpose blocks

__global__ __launch_bounds__(256) void pre_kernel(
        const float* __restrict__ w, float* __restrict__ wT,
        const float* __restrict__ in_spike, float4* __restrict__ spk,
        int* __restrict__ starts) {
    __shared__ float tile[TT][TT + 1];
    __shared__ int hist[257];
    __shared__ int cursor[257];
    __shared__ int wsum[4];

    if (blockIdx.x < NTRANS) {
        const int i0 = (blockIdx.x & (INS / TT - 1)) * TT;
        const int o0 = (blockIdx.x / (INS / TT)) * TT;
        const int c  = threadIdx.x & 63;
        const int r  = threadIdx.x >> 6;
#pragma unroll
        for (int rr = r; rr < TT; rr += 4)
            tile[rr][c] = w[(o0 + rr) * INS + i0 + c];
        __syncthreads();
#pragma unroll
        for (int rr = r; rr < TT; rr += 4)
            wT[(i0 + rr) * OUTS + o0 + c] = tile[c][rr];
        return;
    }

    const int b = blockIdx.x - NTRANS;
    const int tid = threadIdx.x;
    for (int k = tid; k < 257; k += 256) hist[k] = 0;
    __syncthreads();

    float sv[INS / 256];
    int   tv[INS / 256];
#pragma unroll
    for (int j = 0; j < INS / 256; ++j) {
        int i = tid + j * 256;
        float s = in_spike[b * INS + i];
        sv[j] = s;
        int t = (int)floorf(s) + 1;
        t = t < 1 ? 1 : (t > 256 ? 256 : t);
        tv[j] = t;
        atomicAdd(&hist[t], 1);
    }
    __syncthreads();

    // wave-shuffle inclusive scan of hist[1..256] across 4 waves
    const int lane = tid & 63;
    const int wv   = tid >> 6;
    int v = hist[tid + 1];
    int sc = v;
#pragma unroll
    for (int off = 1; off < 64; off <<= 1) {
        int n = __shfl_up(sc, off, 64);
        if (lane >= off) sc += n;
    }
    if (lane == 63) wsum[wv] = sc;
    __syncthreads();
    int base = 0;
    for (int j = 0; j < wv; ++j) base += wsum[j];
    int excl = sc + base - v;             // # spikes with t_on < tid+1
    cursor[tid + 1] = excl;
    starts[b * 258 + tid + 1] = excl;
    if (tid == 0) { starts[b * 258] = 0; starts[b * 258 + 257] = INS; }
    __syncthreads();

#pragma unroll
    for (int j = 0; j < INS / 256; ++j) {
        int i = tid + j * 256;
        int t = tv[j];
        int pos = atomicAdd(&cursor[t], 1);
        float A = expf(fmaf(sv[j], 1.0f / TAUF, 1.0f)) * (1.0f / TAUF);
        float C = -sv[j] * A;
        // y holds BYTE offset of row i in wT viewed as bytes: i*OUTS*4
        spk[b * INS + pos] =
            make_float4(A, __int_as_float(i * (OUTS * 4)), C, __int_as_float(t));
    }
}

// ---------------------------------------------------------------------------
// Scan kernel, SINGLE-PASS with linear snapshots.
// Block = (b, 64 outputs), 1024 threads: threadIdx.x = lane (32) owning
// outputs (2x,2x+1) via float2 gathers; threadIdx.y = g (32) owning time
// window [8g+1, 8g+8].
//
// LATENCY-PIPELINE VERSION: the spike stream is read DIRECTLY from global
// (spk is 16 KB/batch, L1/L2-resident, half-wave-broadcast addresses) in
// QUADS: 4 spike loads issued together, then 4 dependent gathers, then 16
// fma.  Depth-4 VMEM overlap replaces the previous LDS-read -> gather
// depth-~1 serial chain that dominated the kernel.  No sspk staging; LDS
// holds only partials/boundaries (18.5 KB -> 2 blocks/CU trivially).
//
// After bucket d: snapshot l_d = fma(t_d, cA, cC) (linear in running sums).
// Two-level LDS scan over g gives prefix (SA,SC) and totals (TA,TC).
// Check: V(t_d) = fma(t_d, SA, SC) + l_d >= exp2(t_d*log2e/tau).
// Spike-free tail [257,512) split 8 steps per g using totals.  Windows +
// tail partition the time axis -> atomicMin exact.
// Grid = 64*8 = 512 blocks -> 2 blocks/CU = 32 waves/CU.
// ---------------------------------------------------------------------------
#define OL 32            // lanes per block (each owns 2 outputs)
#define G  32            // time windows
#define WS 8             // steps per window (G*WS = 256 covers all t_on)
#define TAIL0 257        // first spike-free time step
#define NGRP 8           // windows per scan group
#define NG (G / NGRP)    // 4 groups

typedef unsigned int u32;

__global__ __launch_bounds__(OL * G, 8) void spike_scan_kernel(
        const float4* __restrict__ spk, const int* __restrict__ starts,
        const float* __restrict__ wT, float* __restrict__ out) {
    const int b = blockIdx.x;
    const int x = threadIdx.x;           // 0..31 lane
    const int g = threadIdx.y;           // 0..31 window
    const int tid = g * OL + x;

    __shared__ float4 sP[G][OL];         // 16 KB (A0,C0,A1,C1) window partials
    __shared__ float4 sQ[NG][OL];        // 2 KB group-inclusive sums
    __shared__ int    sSt[258];          // 1 KB
    __shared__ int    sFirst[2 * OL];    // 256 B

    if (tid < 258) sSt[tid] = starts[b * 258 + tid];
    if (tid < 2 * OL) sFirst[tid] = TSTEPS;
    __syncthreads();

    const int w0 = g * WS + 1;           // first time step of window
    // uniform (SGPR) byte base for this block's output slice; per-lane
    // 32-bit voffset = spike byte offset + x*8  -> saddr-form gathers
    const char* __restrict__ wTb =
        (const char*)wT + ((size_t)blockIdx.y * OL) * sizeof(float2);
    const u32 x8 = (u32)(x << 3);
    const float4* __restrict__ spkb = spk + (size_t)b * INS;

    // ---- single spike walk, bucketed, quad-pipelined, linear snapshots ----
    float cA0 = 0.f, cC0 = 0.f, cA1 = 0.f, cC1 = 0.f;
    float l00, l01, l02, l03, l04, l05, l06, l07;   // output 0 snapshots
    float l10, l11, l12, l13, l14, l15, l16, l17;   // output 1 snapshots
    int k = sSt[w0];

#define FMA2(P, Q)                                                            \
    cA0 = fmaf((Q).x, (P).x, cA0); cC0 = fmaf((Q).x, (P).z, cC0);             \
    cA1 = fmaf((Q).y, (P).x, cA1); cC1 = fmaf((Q).y, (P).z, cC1);

#define BUCKET(D, LA, LB)                                                     \
    {                                                                         \
        const int e = sSt[w0 + (D) + 1];                                      \
        for (; k + 4 <= e; k += 4) {                                          \
            float4 p0 = spkb[k + 0];                                          \
            float4 p1 = spkb[k + 1];                                          \
            float4 p2 = spkb[k + 2];                                          \
            float4 p3 = spkb[k + 3];                                          \
            float2 q0 = *(const float2*)(wTb + ((u32)__float_as_int(p0.y) + x8)); \
            float2 q1 = *(const float2*)(wTb + ((u32)__float_as_int(p1.y) + x8)); \
            float2 q2 = *(const float2*)(wTb + ((u32)__float_as_int(p2.y) + x8)); \
            float2 q3 = *(const float2*)(wTb + ((u32)__float_as_int(p3.y) + x8)); \
            FMA2(p0, q0) FMA2(p1, q1) FMA2(p2, q2) FMA2(p3, q3)               \
        }                                                                     \
        for (; k < e; ++k) {                                                  \
            float4 p = spkb[k];                                               \
            float2 q = *(const float2*)(wTb + ((u32)__float_as_int(p.y) + x8)); \
            FMA2(p, q)                                                        \
        }                                                                     \
        const float tf = (float)(w0 + (D));                                   \
        LA = fmaf(tf, cA0, cC0);                                              \
        LB = fmaf(tf, cA1, cC1);                                              \
    }

    BUCKET(0, l00, l10)
    BUCKET(1, l01, l11)
    BUCKET(2, l02, l12)
    BUCKET(3, l03, l13)
    BUCKET(4, l04, l14)
    BUCKET(5, l05, l15)
    BUCKET(6, l06, l16)
    BUCKET(7, l07, l17)
#undef BUCKET
#undef FMA2

    sP[g][x] = make_float4(cA0, cC0, cA1, cC1);
    __syncthreads();

    // ---- two-level scan over g ----
    // level 1: in-group exclusive prefix (<= NGRP-1 reads, avg 4)
    float SA0 = 0.f, SC0 = 0.f, SA1 = 0.f, SC1 = 0.f;
    {
        const int g0 = g & ~(NGRP - 1);
        for (int j = g0; j < g; ++j) {
            float4 v = sP[j][x];
            SA0 += v.x; SC0 += v.y; SA1 += v.z; SC1 += v.w;
        }
    }
    // group leaders publish group-inclusive sums
    if ((g & (NGRP - 1)) == (NGRP - 1))
        sQ[g >> 3][x] = make_float4(SA0 + cA0, SC0 + cC0, SA1 + cA1, SC1 + cC1);
    __syncthreads();
    // level 2: fold group sums into prefix (groups before mine) and totals
    float TA0 = 0.f, TC0 = 0.f, TA1 = 0.f, TC1 = 0.f;
    {
        const int myg = g >> 3;
#pragma unroll
        for (int s = 0; s < NG; ++s) {
            float4 qv = sQ[s][x];
            TA0 += qv.x; TC0 += qv.y; TA1 += qv.z; TC1 += qv.w;
            if (s < myg) {
                SA0 += qv.x; SC0 += qv.y; SA1 += qv.z; SC1 += qv.w;
            }
        }
    }

    // ---- checks: V(t_d) = fma(t_d, SA, SC) + l_d, branchless mask ----
    unsigned m0 = 0, m1 = 0;
#define CHECK(D, LA, LB)                                                      \
    {                                                                         \
        const float tf = (float)(w0 + (D));                                   \
        const float ev = exp2f(tf * LOG2E_OVER_TAU);                          \
        m0 |= (fmaf(tf, SA0, SC0) + (LA) >= ev) ? (1u << (D)) : 0u;           \
        m1 |= (fmaf(tf, SA1, SC1) + (LB) >= ev) ? (1u << (D)) : 0u;           \
    }
    CHECK(0, l00, l10)
    CHECK(1, l01, l11)
    CHECK(2, l02, l12)
    CHECK(3, l03, l13)
    CHECK(4, l04, l14)
    CHECK(5, l05, l15)
    CHECK(6, l06, l16)
    CHECK(7, l07, l17)
#undef CHECK
    int f0 = m0 ? (w0 + __builtin_ffs(m0) - 1) : TSTEPS;
    int f1 = m1 ? (w0 + __builtin_ffs(m1) - 1) : TSTEPS;

    // ---- distributed spike-free tail [TAIL0, TSTEPS): 8 steps per g ----
    {
        const int t0 = TAIL0 + g * WS;
        unsigned n0 = 0, n1 = 0;
        float tg = (float)t0;
        for (int d = 0; d < WS; ++d) {
            if (t0 + d < TSTEPS) {
                float ev = exp2f(tg * LOG2E_OVER_TAU);
                n0 |= (fmaf(tg, TA0, TC0) >= ev) ? (1u << d) : 0u;
                n1 |= (fmaf(tg, TA1, TC1) >= ev) ? (1u << d) : 0u;
            }
            tg += 1.0f;
        }
        if (n0) f0 = min(f0, t0 + __builtin_ffs(n0) - 1);
        if (n1) f1 = min(f1, t0 + __builtin_ffs(n1) - 1);
    }

    if (f0 < TSTEPS) atomicMin(&sFirst[2 * x], f0);
    if (f1 < TSTEPS) atomicMin(&sFirst[2 * x + 1], f1);
    __syncthreads();
    if (tid < 2 * OL)
        out[b * OUTS + blockIdx.y * (2 * OL) + tid] = (float)sFirst[tid];
}

// ---------------------------------------------------------------------------
extern "C" void kernel_launch(void* const* d_in, const int* in_sizes, int n_in,
                              void* d_out, int out_size, void* d_ws, size_t ws_size,
                              hipStream_t stream) {
    const float* in_spike = (const float*)d_in[0];   // [B, IN] fp32
    const float* weight   = (const float*)d_in[1];   // [OUT, IN] fp32
    float* out = (float*)d_out;                      // [B, OUT] fp32

    // ws layout: wT 2 MB | spk 1 MB | starts 64*258 ints (~66 KB)
    float*  wT     = (float*)d_ws;
    float4* spk    = (float4*)((char*)d_ws + (size_t)INS * OUTS * sizeof(float));
    int*    starts = (int*)((char*)d_ws + (size_t)INS * OUTS * sizeof(float)
                                        + (size_t)BATCH * INS * sizeof(float4));

    pre_kernel<<<NTRANS + BATCH, 256, 0, stream>>>(weight, wT, in_spike, spk, starts);
    spike_scan_kernel<<<dim3(BATCH, OUTS / (2 * OL)), dim3(OL, G), 0, stream>>>(
        spk, starts, wT, out);
}

// Round 3
// 101.192 us; speedup vs baseline: 1.0144x; 1.0144x over previous
//
#include <hip/hip_runtime.h>
#include <math.h>

// Problem constants: B=64, IN=1024, OUT=512, T=512, V_TH=1, TAU=16
#define BATCH   64
#define INS     1024
#define OUTS    512
#define TSTEPS  512
#define TAUF    16.0f
// log2(e)/TAU for exp(t/tau) == exp2(t * LOG2E_OVER_TAU)
#define LOG2E_OVER_TAU 0.0901684400555602f

// ---------------------------------------------------------------------------
// Fused pre-kernel: blocks [0,128) tiled weight transpose w[OUT,IN]->wT[IN,OUT];
// blocks [128,192) per-batch spike prep + counting sort by activation time.
//   alpha(t-s) = e^{-t/tau} * (t*A + C) for t > s,
//   A = exp(1 + s/tau)/tau,  C = -s*A,  t_on = floor(s)+1 in [1,256].
// Record per spike (sorted by t_on): {A, int_bits(i*OUTS*4 BYTE offset), C, t_on}
// Also writes starts[b][tau], tau in [0,257]: # spikes with t_on < tau.
// ---------------------------------------------------------------------------
#define TT 64
#define NTRANS ((INS / TT) * (OUTS / TT))   // 128 transpose blocks

__global__ __launch_bounds__(256) void pre_kernel(
        const float* __restrict__ w, float* __restrict__ wT,
        const float* __restrict__ in_spike, float4* __restrict__ spk,
        int* __restrict__ starts) {
    __shared__ float tile[TT][TT + 1];
    __shared__ int hist[257];
    __shared__ int cursor[257];
    __shared__ int wsum[4];

    if (blockIdx.x < NTRANS) {
        const int i0 = (blockIdx.x & (INS / TT - 1)) * TT;
        const int o0 = (blockIdx.x / (INS / TT)) * TT;
        const int c  = threadIdx.x & 63;
        const int r  = threadIdx.x >> 6;
#pragma unroll
        for (int rr = r; rr < TT; rr += 4)
            tile[rr][c] = w[(o0 + rr) * INS + i0 + c];
        __syncthreads();
#pragma unroll
        for (int rr = r; rr < TT; rr += 4)
            wT[(i0 + rr) * OUTS + o0 + c] = tile[c][rr];
        return;
    }

    const int b = blockIdx.x - NTRANS;
    const int tid = threadIdx.x;
    for (int k = tid; k < 257; k += 256) hist[k] = 0;
    __syncthreads();

    float sv[INS / 256];
    int   tv[INS / 256];
#pragma unroll
    for (int j = 0; j < INS / 256; ++j) {
        int i = tid + j * 256;
        float s = in_spike[b * INS + i];
        sv[j] = s;
        int t = (int)floorf(s) + 1;
        t = t < 1 ? 1 : (t > 256 ? 256 : t);
        tv[j] = t;
        atomicAdd(&hist[t], 1);
    }
    __syncthreads();

    // wave-shuffle inclusive scan of hist[1..256] across 4 waves
    const int lane = tid & 63;
    const int wv   = tid >> 6;
    int v = hist[tid + 1];
    int sc = v;
#pragma unroll
    for (int off = 1; off < 64; off <<= 1) {
        int n = __shfl_up(sc, off, 64);
        if (lane >= off) sc += n;
    }
    if (lane == 63) wsum[wv] = sc;
    __syncthreads();
    int base = 0;
    for (int j = 0; j < wv; ++j) base += wsum[j];
    int excl = sc + base - v;             // # spikes with t_on < tid+1
    cursor[tid + 1] = excl;
    starts[b * 258 + tid + 1] = excl;
    if (tid == 0) { starts[b * 258] = 0; starts[b * 258 + 257] = INS; }
    __syncthreads();

#pragma unroll
    for (int j = 0; j < INS / 256; ++j) {
        int i = tid + j * 256;
        int t = tv[j];
        int pos = atomicAdd(&cursor[t], 1);
        float A = expf(fmaf(sv[j], 1.0f / TAUF, 1.0f)) * (1.0f / TAUF);
        float C = -sv[j] * A;
        // y holds BYTE offset of row i in wT viewed as bytes: i*OUTS*4
        spk[b * INS + pos] =
            make_float4(A, __int_as_float(i * (OUTS * 4)), C, __int_as_float(t));
    }
}

// ---------------------------------------------------------------------------
// Scan kernel.  Block = (b, 64 outputs), 1024 threads: threadIdx.x = lane
// (32) owning outputs (2x,2x+1) via float2 gathers; threadIdx.y = g (32)
// owning time window [8g+1, 8g+8].
//
// COLD-L2 FIX (round-3): the harness's poison fill flushes L2 every
// iteration, so all wT gathers were 900-cyc HBM misses at depth ~4/wave
// (-> the measured 47 us).  Each block now STREAMS a 32 KB stripe of wT
// (stripe = bid/8; blocks round-robin over the 8 XCDs, so the 64 blocks
// per XCD cover all 64 stripes -> full 2 MB of wT lands in every XCD L2
// at full BW, ~3 us).  Same compulsory HBM bytes as before, but streamed;
// the gather walk then runs at ~200-cyc L2-hit latency.
//
// Walk: spikes staged to LDS (global_load_lds, short lgkm hop feeds the
// gather address), quad-unrolled buckets (depth-4 gather MLP), linear
// snapshots l_d = fma(t_d, cA, cC) after each bucket.  Two-level LDS scan
// over g gives prefix (SA,SC) and totals (TA,TC).  Check:
//   V(t_d) = fma(t_d, SA, SC) + l_d >= exp2(t_d*log2e/tau).
// Spike-free tail [257,512) split 8 steps per g using totals.  Windows +
// tail partition the time axis -> atomicMin exact.
// Grid = 64*8 = 512 blocks -> 2 blocks/CU = 32 waves/CU.
// ---------------------------------------------------------------------------
#define OL 32            // lanes per block (each owns 2 outputs)
#define G  32            // time windows
#define WS 8             // steps per window (G*WS = 256 covers all t_on)
#define TAIL0 257        // first spike-free time step
#define NGRP 8           // windows per scan group
#define NG (G / NGRP)    // 4 groups

typedef unsigned int u32;

__global__ __launch_bounds__(OL * G, 8) void spike_scan_kernel(
        const float4* __restrict__ spk, const int* __restrict__ starts,
        const float* __restrict__ wT, float* __restrict__ out) {
    const int b = blockIdx.x;
    const int x = threadIdx.x;           // 0..31 lane
    const int g = threadIdx.y;           // 0..31 window
    const int tid = g * OL + x;

    __shared__ float4 sspk[INS];         // 16 KB
    __shared__ float4 sP[G][OL];         // 16 KB (A0,C0,A1,C1) window partials
    __shared__ float4 sQ[NG][OL];        // 2 KB group-inclusive sums
    __shared__ int    sSt[258];          // 1 KB
    __shared__ int    sFirst[2 * OL];    // 256 B

    // direct global->LDS staging of this batch's spike stream (16 B/lane)
    {
        auto gsrc = (const __attribute__((address_space(1))) u32*)
                        (spk + (size_t)b * INS + tid);
        auto ldst = (__attribute__((address_space(3))) u32*)&sspk[tid];
        __builtin_amdgcn_global_load_lds(gsrc, ldst, 16, 0, 0);
    }

    // ---- L2 warm: stream one 32 KB stripe of wT into this XCD's L2 ----
    // bid runs 0..511; XCD = bid % 8 (round-robin dispatch), so the 64
    // blocks of one XCD carry distinct bid/8 in [0,64) -> stripes tile wT.
    {
        const int bid = blockIdx.y * gridDim.x + blockIdx.x;
        const float4* wp = (const float4*)wT + ((size_t)(bid >> 3) << 11);
        float4 wa = wp[tid];
        float4 wb = wp[tid + 1024];
        asm volatile("" :: "v"(wa.x), "v"(wa.y), "v"(wa.z), "v"(wa.w),
                           "v"(wb.x), "v"(wb.y), "v"(wb.z), "v"(wb.w));
    }

    if (tid < 258) sSt[tid] = starts[b * 258 + tid];
    if (tid < 2 * OL) sFirst[tid] = TSTEPS;
    __syncthreads();

    const int w0 = g * WS + 1;           // first time step of window
    // uniform (SGPR) byte base for this block's output slice; per-lane
    // 32-bit voffset = spike byte offset + x*8  -> saddr-form gathers
    const char* __restrict__ wTb =
        (const char*)wT + ((size_t)blockIdx.y * OL) * sizeof(float2);
    const u32 x8 = (u32)(x << 3);

    // ---- single spike walk, bucketed, quad-pipelined, linear snapshots ----
    float cA0 = 0.f, cC0 = 0.f, cA1 = 0.f, cC1 = 0.f;
    float l00, l01, l02, l03, l04, l05, l06, l07;   // output 0 snapshots
    float l10, l11, l12, l13, l14, l15, l16, l17;   // output 1 snapshots
    int k = sSt[w0];

#define FMA2(P, Q)                                                            \
    cA0 = fmaf((Q).x, (P).x, cA0); cC0 = fmaf((Q).x, (P).z, cC0);             \
    cA1 = fmaf((Q).y, (P).x, cA1); cC1 = fmaf((Q).y, (P).z, cC1);

#define BUCKET(D, LA, LB)                                                     \
    {                                                                         \
        const int e = sSt[w0 + (D) + 1];                                      \
        for (; k + 4 <= e; k += 4) {                                          \
            float4 p0 = sspk[k + 0];                                          \
            float4 p1 = sspk[k + 1];                                          \
            float4 p2 = sspk[k + 2];                                          \
            float4 p3 = sspk[k + 3];                                          \
            float2 q0 = *(const float2*)(wTb + ((u32)__float_as_int(p0.y) + x8)); \
            float2 q1 = *(const float2*)(wTb + ((u32)__float_as_int(p1.y) + x8)); \
            float2 q2 = *(const float2*)(wTb + ((u32)__float_as_int(p2.y) + x8)); \
            float2 q3 = *(const float2*)(wTb + ((u32)__float_as_int(p3.y) + x8)); \
            FMA2(p0, q0) FMA2(p1, q1) FMA2(p2, q2) FMA2(p3, q3)               \
        }                                                                     \
        for (; k < e; ++k) {                                                  \
            float4 p = sspk[k];                                               \
            float2 q = *(const float2*)(wTb + ((u32)__float_as_int(p.y) + x8)); \
            FMA2(p, q)                                                        \
        }                                                                     \
        const float tf = (float)(w0 + (D));                                   \
        LA = fmaf(tf, cA0, cC0);                                              \
        LB = fmaf(tf, cA1, cC1);                                              \
    }

    BUCKET(0, l00, l10)
    BUCKET(1, l01, l11)
    BUCKET(2, l02, l12)
    BUCKET(3, l03, l13)
    BUCKET(4, l04, l14)
    BUCKET(5, l05, l15)
    BUCKET(6, l06, l16)
    BUCKET(7, l07, l17)
#undef BUCKET
#undef FMA2

    sP[g][x] = make_float4(cA0, cC0, cA1, cC1);
    __syncthreads();

    // ---- two-level scan over g ----
    // level 1: in-group exclusive prefix (<= NGRP-1 reads, avg 4)
    float SA0 = 0.f, SC0 = 0.f, SA1 = 0.f, SC1 = 0.f;
    {
        const int g0 = g & ~(NGRP - 1);
        for (int j = g0; j < g; ++j) {
            float4 v = sP[j][x];
            SA0 += v.x; SC0 += v.y; SA1 += v.z; SC1 += v.w;
        }
    }
    // group leaders publish group-inclusive sums
    if ((g & (NGRP - 1)) == (NGRP - 1))
        sQ[g >> 3][x] = make_float4(SA0 + cA0, SC0 + cC0, SA1 + cA1, SC1 + cC1);
    __syncthreads();
    // level 2: fold group sums into prefix (groups before mine) and totals
    float TA0 = 0.f, TC0 = 0.f, TA1 = 0.f, TC1 = 0.f;
    {
        const int myg = g >> 3;
#pragma unroll
        for (int s = 0; s < NG; ++s) {
            float4 qv = sQ[s][x];
            TA0 += qv.x; TC0 += qv.y; TA1 += qv.z; TC1 += qv.w;
            if (s < myg) {
                SA0 += qv.x; SC0 += qv.y; SA1 += qv.z; SC1 += qv.w;
            }
        }
    }

    // ---- checks: V(t_d) = fma(t_d, SA, SC) + l_d, branchless mask ----
    unsigned m0 = 0, m1 = 0;
#define CHECK(D, LA, LB)                                                      \
    {                                                                         \
        const float tf = (float)(w0 + (D));                                   \
        const float ev = exp2f(tf * LOG2E_OVER_TAU);                          \
        m0 |= (fmaf(tf, SA0, SC0) + (LA) >= ev) ? (1u << (D)) : 0u;           \
        m1 |= (fmaf(tf, SA1, SC1) + (LB) >= ev) ? (1u << (D)) : 0u;           \
    }
    CHECK(0, l00, l10)
    CHECK(1, l01, l11)
    CHECK(2, l02, l12)
    CHECK(3, l03, l13)
    CHECK(4, l04, l14)
    CHECK(5, l05, l15)
    CHECK(6, l06, l16)
    CHECK(7, l07, l17)
#undef CHECK
    int f0 = m0 ? (w0 + __builtin_ffs(m0) - 1) : TSTEPS;
    int f1 = m1 ? (w0 + __builtin_ffs(m1) - 1) : TSTEPS;

    // ---- distributed spike-free tail [TAIL0, TSTEPS): 8 steps per g ----
    {
        const int t0 = TAIL0 + g * WS;
        unsigned n0 = 0, n1 = 0;
        float tg = (float)t0;
        for (int d = 0; d < WS; ++d) {
            if (t0 + d < TSTEPS) {
                float ev = exp2f(tg * LOG2E_OVER_TAU);
                n0 |= (fmaf(tg, TA0, TC0) >= ev) ? (1u << d) : 0u;
                n1 |= (fmaf(tg, TA1, TC1) >= ev) ? (1u << d) : 0u;
            }
            tg += 1.0f;
        }
        if (n0) f0 = min(f0, t0 + __builtin_ffs(n0) - 1);
        if (n1) f1 = min(f1, t0 + __builtin_ffs(n1) - 1);
    }

    if (f0 < TSTEPS) atomicMin(&sFirst[2 * x], f0);
    if (f1 < TSTEPS) atomicMin(&sFirst[2 * x + 1], f1);
    __syncthreads();
    if (tid < 2 * OL)
        out[b * OUTS + blockIdx.y * (2 * OL) + tid] = (float)sFirst[tid];
}

// ---------------------------------------------------------------------------
extern "C" void kernel_launch(void* const* d_in, const int* in_sizes, int n_in,
                              void* d_out, int out_size, void* d_ws, size_t ws_size,
                              hipStream_t stream) {
    const float* in_spike = (const float*)d_in[0];   // [B, IN] fp32
    const float* weight   = (const float*)d_in[1];   // [OUT, IN] fp32
    float* out = (float*)d_out;                      // [B, OUT] fp32

    // ws layout: wT 2 MB | spk 1 MB | starts 64*258 ints (~66 KB)
    float*  wT     = (float*)d_ws;
    float4* spk    = (float4*)((char*)d_ws + (size_t)INS * OUTS * sizeof(float));
    int*    starts = (int*)((char*)d_ws + (size_t)INS * OUTS * sizeof(float)
                                        + (size_t)BATCH * INS * sizeof(float4));

    pre_kernel<<<NTRANS + BATCH, 256, 0, stream>>>(weight, wT, in_spike, spk, starts);
    spike_scan_kernel<<<dim3(BATCH, OUTS / (2 * OL)), dim3(OL, G), 0, stream>>>(
        spk, starts, wT, out);
}

// Round 4
// 84.113 us; speedup vs baseline: 1.2203x; 1.2031x over previous
//
#include <hip/hip_runtime.h>
#include <math.h>

// Problem constants: B=64, IN=1024, OUT=512, T=512, V_TH=1, TAU=16
#define BATCH   64
#define INS     1024
#define OUTS    512
#define TSTEPS  512
#define TAUF    16.0f
// log2(e)/TAU for exp(t/tau) == exp2(t * LOG2E_OVER_TAU)
#define LOG2E_OVER_TAU 0.0901684400555602f

// ---------------------------------------------------------------------------
// Fused pre-kernel: blocks [0,128) tiled weight transpose w[OUT,IN]->wT[IN,OUT];
// blocks [128,192) per-batch spike prep + counting sort by activation time.
//   alpha(t-s) = e^{-t/tau} * (t*A + C) for t > s,
//   A = exp(1 + s/tau)/tau,  C = -s*A,  t_on = floor(s)+1 in [1,256].
// Record per spike (sorted by t_on): {A, int_bits(i*OUTS*4 BYTE offset), C, t_on}
// Also writes starts[b][tau], tau in [0,257]: # spikes with t_on < tau.
// ---------------------------------------------------------------------------
#define TT 64
#define NTRANS ((INS / TT) * (OUTS / TT))   // 128 transpose blocks

__global__ __launch_bounds__(256) void pre_kernel(
        const float* __restrict__ w, float* __restrict__ wT,
        const float* __restrict__ in_spike, float4* __restrict__ spk,
        int* __restrict__ starts) {
    __shared__ float tile[TT][TT + 1];
    __shared__ int hist[257];
    __shared__ int cursor[257];
    __shared__ int wsum[4];

    if (blockIdx.x < NTRANS) {
        const int i0 = (blockIdx.x & (INS / TT - 1)) * TT;
        const int o0 = (blockIdx.x / (INS / TT)) * TT;
        const int c  = threadIdx.x & 63;
        const int r  = threadIdx.x >> 6;
#pragma unroll
        for (int rr = r; rr < TT; rr += 4)
            tile[rr][c] = w[(o0 + rr) * INS + i0 + c];
        __syncthreads();
#pragma unroll
        for (int rr = r; rr < TT; rr += 4)
            wT[(i0 + rr) * OUTS + o0 + c] = tile[c][rr];
        return;
    }

    const int b = blockIdx.x - NTRANS;
    const int tid = threadIdx.x;
    for (int k = tid; k < 257; k += 256) hist[k] = 0;
    __syncthreads();

    float sv[INS / 256];
    int   tv[INS / 256];
#pragma unroll
    for (int j = 0; j < INS / 256; ++j) {
        int i = tid + j * 256;
        float s = in_spike[b * INS + i];
        sv[j] = s;
        int t = (int)floorf(s) + 1;
        t = t < 1 ? 1 : (t > 256 ? 256 : t);
        tv[j] = t;
        atomicAdd(&hist[t], 1);
    }
    __syncthreads();

    // wave-shuffle inclusive scan of hist[1..256] across 4 waves
    const int lane = tid & 63;
    const int wv   = tid >> 6;
    int v = hist[tid + 1];
    int sc = v;
#pragma unroll
    for (int off = 1; off < 64; off <<= 1) {
        int n = __shfl_up(sc, off, 64);
        if (lane >= off) sc += n;
    }
    if (lane == 63) wsum[wv] = sc;
    __syncthreads();
    int base = 0;
    for (int j = 0; j < wv; ++j) base += wsum[j];
    int excl = sc + base - v;             // # spikes with t_on < tid+1
    cursor[tid + 1] = excl;
    starts[b * 258 + tid + 1] = excl;
    if (tid == 0) { starts[b * 258] = 0; starts[b * 258 + 257] = INS; }
    __syncthreads();

#pragma unroll
    for (int j = 0; j < INS / 256; ++j) {
        int i = tid + j * 256;
        int t = tv[j];
        int pos = atomicAdd(&cursor[t], 1);
        float A = expf(fmaf(sv[j], 1.0f / TAUF, 1.0f)) * (1.0f / TAUF);
        float C = -sv[j] * A;
        // y holds BYTE offset of row i in wT viewed as bytes: i*OUTS*4
        spk[b * INS + pos] =
            make_float4(A, __int_as_float(i * (OUTS * 4)), C, __int_as_float(t));
    }
}

// ---------------------------------------------------------------------------
// Scan kernel, FLAT PREDICATED WALK (round-4).
//
// Diagnosis history: bucket-by-bucket walks serialize on {ds_read ->
// gather -> wait} chains at ~4 spikes/bucket (L2-hit latency x 8 buckets;
// warm-L2 probe was neutral -> chain-depth, not residency, is the limit).
//
// Fix: one flat loop over the window's whole spike range, unroll 4, NO
// remainder, NO interior boundaries.  Every slot contributes to all WS
// per-step prefixes via predicated FMA:
//    PA[d] += q * ((t_on <= w0+d) ? A : 0)    (exact: adds 0.0 when off)
// All loads in an iteration are address-independent -> MLP 4 on ds_read
// + MLP 4 on gathers, no waits between buckets.  FP accumulation order
// for active terms is the sorted spike order (same as before).
//
// Reshape: WS=4, G=64 windows, OL=16 lanes x 4 outputs (float4 gathers).
// Per-thread walk halves to ~16 spikes; predication cost/thread halves.
// Two-level scan over g (8 groups of 8) gives prefix (SA,SC) and totals
// (TA,TC).  Check: V(t_d) = fma(t_d,SA,SC) + fma(t_d,PA[d],PC[d]) >= ev.
// Spike-free tail [257,512) split 4 steps per g using totals.  Windows +
// tail partition the time axis -> atomicMin exact.
// Grid = 64*8 = 512 blocks of 1024 threads.
// ---------------------------------------------------------------------------
#define OL 16            // lanes per block (each owns 4 outputs)
#define G  64            // time windows
#define WS 4             // steps per window (G*WS = 256 covers all t_on)
#define TAIL0 257        // first spike-free time step
#define NGRP 8           // windows per scan group
#define NG (G / NGRP)    // 8 groups

typedef unsigned int u32;

__global__ __launch_bounds__(OL * G, 4) void spike_scan_kernel(
        const float4* __restrict__ spk, const int* __restrict__ starts,
        const float* __restrict__ wT, float* __restrict__ out) {
    const int b = blockIdx.x;
    const int x = threadIdx.x;           // 0..15 lane
    const int g = threadIdx.y;           // 0..63 window
    const int tid = g * OL + x;

    __shared__ float4 sspk[INS + 4];     // 16.4 KB (+4 pad slots)
    __shared__ float4 sPA[G][OL];        // 16 KB window-total A sums
    __shared__ float4 sPC[G][OL];        // 16 KB window-total C sums
    __shared__ float4 sQA[NG][OL];       // 2 KB group-inclusive A
    __shared__ float4 sQC[NG][OL];       // 2 KB group-inclusive C
    __shared__ int    sSt[258];          // 1 KB
    __shared__ int    sFirst[4 * OL];    // 256 B

    // direct global->LDS staging of this batch's spike stream (16 B/lane)
    {
        auto gsrc = (const __attribute__((address_space(1))) u32*)
                        (spk + (size_t)b * INS + tid);
        auto ldst = (__attribute__((address_space(3))) u32*)&sspk[tid];
        __builtin_amdgcn_global_load_lds(gsrc, ldst, 16, 0, 0);
    }
    // pad slots: A=C=0, t_on=huge -> all predicates false, gather hits wT[0]
    if (tid < 4)
        sspk[INS + tid] = make_float4(0.f, __int_as_float(0),
                                      0.f, __int_as_float(1 << 30));
    if (tid < 258) sSt[tid] = starts[b * 258 + tid];
    if (tid < 4 * OL) sFirst[tid] = TSTEPS;
    __syncthreads();

    const int w0 = g * WS + 1;           // first time step of window
    // uniform (SGPR) byte base for this block's 64-output slice; per-lane
    // 32-bit voffset = spike byte offset + x*16 -> saddr float4 gathers
    const char* __restrict__ wTb =
        (const char*)wT + (size_t)blockIdx.y * (4 * OL) * sizeof(float);
    const u32 x16 = (u32)(x << 4);

    // ---- flat predicated walk over [s, e), unroll 4, no remainder ----
    const int s = sSt[w0];
    const int e = sSt[w0 + WS];

    float4 PA[WS], PC[WS];
#pragma unroll
    for (int d = 0; d < WS; ++d) {
        PA[d] = make_float4(0.f, 0.f, 0.f, 0.f);
        PC[d] = make_float4(0.f, 0.f, 0.f, 0.f);
    }

    for (int k = s; k < e; k += 4) {
#pragma unroll
        for (int j = 0; j < 4; ++j) {
            const float4 p = sspk[k + j];
            const float4 q = *(const float4*)(
                wTb + ((u32)__float_as_int(p.y) + x16));
            const int ton = __float_as_int(p.w);
#pragma unroll
            for (int d = 0; d < WS; ++d) {
                const bool on = (ton <= w0 + d);
                const float Ad = on ? p.x : 0.0f;
                const float Cd = on ? p.z : 0.0f;
                PA[d].x = fmaf(q.x, Ad, PA[d].x);
                PC[d].x = fmaf(q.x, Cd, PC[d].x);
                PA[d].y = fmaf(q.y, Ad, PA[d].y);
                PC[d].y = fmaf(q.y, Cd, PC[d].y);
                PA[d].z = fmaf(q.z, Ad, PA[d].z);
                PC[d].z = fmaf(q.z, Cd, PC[d].z);
                PA[d].w = fmaf(q.w, Ad, PA[d].w);
                PC[d].w = fmaf(q.w, Cd, PC[d].w);
            }
        }
    }

    sPA[g][x] = PA[WS - 1];
    sPC[g][x] = PC[WS - 1];
    __syncthreads();

    // ---- two-level scan over g: prefix (SA,SC), totals (TA,TC) ----
    float4 SA = make_float4(0.f, 0.f, 0.f, 0.f);
    float4 SC = make_float4(0.f, 0.f, 0.f, 0.f);
    {
        const int g0 = g & ~(NGRP - 1);
        for (int j = g0; j < g; ++j) {
            float4 a = sPA[j][x], c = sPC[j][x];
            SA.x += a.x; SA.y += a.y; SA.z += a.z; SA.w += a.w;
            SC.x += c.x; SC.y += c.y; SC.z += c.z; SC.w += c.w;
        }
    }
    if ((g & (NGRP - 1)) == (NGRP - 1)) {
        sQA[g >> 3][x] = make_float4(SA.x + PA[WS-1].x, SA.y + PA[WS-1].y,
                                     SA.z + PA[WS-1].z, SA.w + PA[WS-1].w);
        sQC[g >> 3][x] = make_float4(SC.x + PC[WS-1].x, SC.y + PC[WS-1].y,
                                     SC.z + PC[WS-1].z, SC.w + PC[WS-1].w);
    }
    __syncthreads();
    float4 TA = make_float4(0.f, 0.f, 0.f, 0.f);
    float4 TC = make_float4(0.f, 0.f, 0.f, 0.f);
    {
        const int myg = g >> 3;
#pragma unroll
        for (int ss = 0; ss < NG; ++ss) {
            float4 qa = sQA[ss][x], qc = sQC[ss][x];
            TA.x += qa.x; TA.y += qa.y; TA.z += qa.z; TA.w += qa.w;
            TC.x += qc.x; TC.y += qc.y; TC.z += qc.z; TC.w += qc.w;
            if (ss < myg) {
                SA.x += qa.x; SA.y += qa.y; SA.z += qa.z; SA.w += qa.w;
                SC.x += qc.x; SC.y += qc.y; SC.z += qc.z; SC.w += qc.w;
            }
        }
    }

    // ---- checks: V(t_d) = fma(t_d,SA,SC) + fma(t_d,PA[d],PC[d]) ----
    u32 m0 = 0, m1 = 0, m2 = 0, m3 = 0;
#pragma unroll
    for (int d = 0; d < WS; ++d) {
        const float tf = (float)(w0 + d);
        const float ev = exp2f(tf * LOG2E_OVER_TAU);
        m0 |= (fmaf(tf, SA.x, SC.x) + fmaf(tf, PA[d].x, PC[d].x) >= ev)
                  ? (1u << d) : 0u;
        m1 |= (fmaf(tf, SA.y, SC.y) + fmaf(tf, PA[d].y, PC[d].y) >= ev)
                  ? (1u << d) : 0u;
        m2 |= (fmaf(tf, SA.z, SC.z) + fmaf(tf, PA[d].z, PC[d].z) >= ev)
                  ? (1u << d) : 0u;
        m3 |= (fmaf(tf, SA.w, SC.w) + fmaf(tf, PA[d].w, PC[d].w) >= ev)
                  ? (1u << d) : 0u;
    }
    int f0 = m0 ? (w0 + __builtin_ffs(m0) - 1) : TSTEPS;
    int f1 = m1 ? (w0 + __builtin_ffs(m1) - 1) : TSTEPS;
    int f2 = m2 ? (w0 + __builtin_ffs(m2) - 1) : TSTEPS;
    int f3 = m3 ? (w0 + __builtin_ffs(m3) - 1) : TSTEPS;

    // ---- distributed spike-free tail [TAIL0, TSTEPS): 4 steps per g ----
    {
        const int t0 = TAIL0 + g * WS;
        u32 n0 = 0, n1 = 0, n2 = 0, n3 = 0;
        float tg = (float)t0;
#pragma unroll
        for (int d = 0; d < WS; ++d) {
            if (t0 + d < TSTEPS) {
                const float ev = exp2f(tg * LOG2E_OVER_TAU);
                n0 |= (fmaf(tg, TA.x, TC.x) >= ev) ? (1u << d) : 0u;
                n1 |= (fmaf(tg, TA.y, TC.y) >= ev) ? (1u << d) : 0u;
                n2 |= (fmaf(tg, TA.z, TC.z) >= ev) ? (1u << d) : 0u;
                n3 |= (fmaf(tg, TA.w, TC.w) >= ev) ? (1u << d) : 0u;
            }
            tg += 1.0f;
        }
        if (n0) f0 = min(f0, t0 + __builtin_ffs(n0) - 1);
        if (n1) f1 = min(f1, t0 + __builtin_ffs(n1) - 1);
        if (n2) f2 = min(f2, t0 + __builtin_ffs(n2) - 1);
        if (n3) f3 = min(f3, t0 + __builtin_ffs(n3) - 1);
    }

    if (f0 < TSTEPS) atomicMin(&sFirst[4 * x + 0], f0);
    if (f1 < TSTEPS) atomicMin(&sFirst[4 * x + 1], f1);
    if (f2 < TSTEPS) atomicMin(&sFirst[4 * x + 2], f2);
    if (f3 < TSTEPS) atomicMin(&sFirst[4 * x + 3], f3);
    __syncthreads();
    if (tid < 4 * OL)
        out[b * OUTS + blockIdx.y * (4 * OL) + tid] = (float)sFirst[tid];
}

// ---------------------------------------------------------------------------
extern "C" void kernel_launch(void* const* d_in, const int* in_sizes, int n_in,
                              void* d_out, int out_size, void* d_ws, size_t ws_size,
                              hipStream_t stream) {
    const float* in_spike = (const float*)d_in[0];   // [B, IN] fp32
    const float* weight   = (const float*)d_in[1];   // [OUT, IN] fp32
    float* out = (float*)d_out;                      // [B, OUT] fp32

    // ws layout: wT 2 MB | spk 1 MB | starts 64*258 ints (~66 KB)
    float*  wT     = (float*)d_ws;
    float4* spk    = (float4*)((char*)d_ws + (size_t)INS * OUTS * sizeof(float));
    int*    starts = (int*)((char*)d_ws + (size_t)INS * OUTS * sizeof(float)
                                        + (size_t)BATCH * INS * sizeof(float4));

    pre_kernel<<<NTRANS + BATCH, 256, 0, stream>>>(weight, wT, in_spike, spk, starts);
    spike_scan_kernel<<<dim3(BATCH, OUTS / (4 * OL)), dim3(OL, G), 0, stream>>>(
        spk, starts, wT, out);
}